// Round 5
// baseline (581.582 us; speedup 1.0000x reference)
//
#include <hip/hip_runtime.h>
#include <math.h>

// ---- problem constants ----
// B=8, H=W=D=32, V=32768 per batch, S=64
// outputs (flat, in return order):
//   sampled [8,32,32,32]         -> 262144  @ 0
//   E       [8,3,3]              -> 72      @ 262144
//   coords  [8,32,32,32,3]       -> 786432  @ 262216
//   points_code [8,32768,384]    -> 100663296 @ 1048648
#define OFF_E     262144
#define OFF_COORD 262216
#define OFF_CODE  1048648

#define QUAD 0.19634954084936207f   // 4*pi/64

// ---- ws layout (floats) ----
#define WS_H1 0
#define WS_H2 32768
#define WS_C  98304
#define WS_AB 106496
#define WS_ZT 110592            // 16 planes x 32768 per batch, transposed
#define ZT_PER_B (16 * 32768)   // 524288 floats per batch
// plane map: 0..2 = P1 (y,z,x)*r ; 3 = r^2 ; 4..10 = P3(m9..15)*r^3 ;
//            11..15 = P2(m4..8)*r^2

typedef float v4f __attribute__((ext_vector_type(4)));

__device__ __forceinline__ void nt_store4(float* p, float a, float b, float c, float d) {
    v4f v = {a, b, c, d};
    __builtin_nontemporal_store(v, (v4f*)p);
}
__device__ __forceinline__ void nt_store1(float* p, float a) {
    __builtin_nontemporal_store(a, p);
}

// ============================================================
// Kernel 1a: hidden layers.  grid 64 = 8 batches x 8 row-groups, 384 thr
// ============================================================
__global__ __launch_bounds__(384) void k_hidden(
    const float* __restrict__ F,
    const float* __restrict__ bw1, const float* __restrict__ bb1,
    const float* __restrict__ cw1, const float* __restrict__ cb1,
    float* __restrict__ ws)
{
    __shared__ float sF[8 * 257];   // +1 pad: rows hit distinct banks
    const int blk = blockIdx.x;
    const int b   = blk >> 3;
    const int r0  = (blk & 7) * 8;
    const int tid = threadIdx.x;

    float* wsH1 = ws + WS_H1;
    float* wsH2 = ws + WS_H2;

    const float* Fb = F + ((size_t)b * 64 + r0) * 256;
    for (int i = tid; i < 2048; i += 384) sF[(i >> 8) * 257 + (i & 255)] = Fb[i];
    __syncthreads();

    if (tid < 128) {
        const int row = tid >> 4, k4 = (tid & 15) * 4;
        const float* fr = sF + row * 257;
        float4 acc = *(const float4*)&bb1[k4];
        #pragma unroll 4
        for (int j = 0; j < 256; ++j) {
            const float  f = fr[j];
            const float4 w = *(const float4*)&bw1[j * 64 + k4];
            acc.x = fmaf(f, w.x, acc.x);
            acc.y = fmaf(f, w.y, acc.y);
            acc.z = fmaf(f, w.z, acc.z);
            acc.w = fmaf(f, w.w, acc.w);
        }
        acc.x = fmaxf(acc.x, 0.f); acc.y = fmaxf(acc.y, 0.f);
        acc.z = fmaxf(acc.z, 0.f); acc.w = fmaxf(acc.w, 0.f);
        *(float4*)&wsH1[((size_t)b * 64 + r0 + row) * 64 + k4] = acc;
    } else {
        const int tt  = tid - 128;
        const int row = tt >> 5, k4 = (tt & 31) * 4;
        const float* fr = sF + row * 257;
        float4 acc = *(const float4*)&cb1[k4];
        #pragma unroll 4
        for (int j = 0; j < 256; ++j) {
            const float  f = fr[j];
            const float4 w = *(const float4*)&cw1[j * 128 + k4];
            acc.x = fmaf(f, w.x, acc.x);
            acc.y = fmaf(f, w.y, acc.y);
            acc.z = fmaf(f, w.z, acc.z);
            acc.w = fmaf(f, w.w, acc.w);
        }
        acc.x = fmaxf(acc.x, 0.f); acc.y = fmaxf(acc.y, 0.f);
        acc.z = fmaxf(acc.z, 0.f); acc.w = fmaxf(acc.w, 0.f);
        *(float4*)&wsH2[((size_t)b * 64 + r0 + row) * 128 + k4] = acc;
    }
}

// ============================================================
// Kernel 1b: latent, basis, Y(S2), coeffs, E, A/B.  grid 8, 512 thr
// ============================================================
__global__ __launch_bounds__(512) void k_coeffs(
    const float* __restrict__ ws_in,
    const float* __restrict__ S2,
    const float* __restrict__ bw2, const float* __restrict__ bb2,
    const float* __restrict__ cw2, const float* __restrict__ cb2,
    const float* __restrict__ iw,
    float* __restrict__ ws_out, float* __restrict__ outE)
{
    __shared__ float sH2[64 * 129];             // padded stride
    __shared__ alignas(16) float sLat[64 * 64];
    __shared__ float sY[64 * 16];
    __shared__ float sBas[64 * 3];
    __shared__ float sC[16 * 64];
    __shared__ float sE[9];

    const int b = blockIdx.x, tid = threadIdx.x;
    const float* wsH1 = ws_in + WS_H1;
    const float* wsH2 = ws_in + WS_H2;
    float* wsC  = ws_out + WS_C;
    float* wsAB = ws_out + WS_AB;

    const float* H2b = wsH2 + (size_t)b * 8192;
    for (int i = tid; i < 8192; i += 512) sH2[(i >> 7) * 129 + (i & 127)] = H2b[i];

    if (tid < 64) {
        const float x = S2[tid * 3 + 0], y = S2[tid * 3 + 1], z = S2[tid * 3 + 2];
        float* Yv = sY + tid * 16;
        Yv[0]  = 0.28209479f;
        Yv[1]  = 0.48860251f * y;
        Yv[2]  = 0.48860251f * z;
        Yv[3]  = 0.48860251f * x;
        Yv[4]  = 1.09254843f * x * y;
        Yv[5]  = 1.09254843f * y * z;
        Yv[6]  = 0.31539157f * (3.f * z * z - 1.f);
        Yv[7]  = 1.09254843f * x * z;
        Yv[8]  = 0.54627421f * (x * x - y * y);
        Yv[9]  = 0.59004359f * y * (3.f * x * x - y * y);
        Yv[10] = 2.89061144f * x * y * z;
        Yv[11] = 0.45704579f * y * (5.f * z * z - 1.f);
        Yv[12] = 0.37317633f * z * (5.f * z * z - 3.f);
        Yv[13] = 0.45704579f * x * (5.f * z * z - 1.f);
        Yv[14] = 1.44530572f * z * (x * x - y * y);
        Yv[15] = 0.59004359f * x * (x * x - 3.f * y * y);
    }

    float breg = 0.f;
    if (tid < 192) {
        const int v = tid / 3, c = tid % 3;
        const float* h1 = wsH1 + ((size_t)b * 64 + v) * 64;
        float acc = bb2[c];
        #pragma unroll 8
        for (int k = 0; k < 64; ++k) acc = fmaf(h1[k], bw2[k * 3 + c], acc);
        breg = acc;
    }
    __syncthreads();   // sH2, sY ready

    if (tid < 192) sBas[tid] = breg;

    for (int t = tid; t < 1024; t += 512) {
        const int row = t >> 4, i4 = (t & 15) * 4;
        const float* h2 = sH2 + row * 129;
        float4 acc = *(const float4*)&cb2[i4];
        #pragma unroll 4
        for (int k = 0; k < 128; ++k) {
            const float  h = h2[k];
            const float4 w = *(const float4*)&cw2[k * 64 + i4];
            acc.x = fmaf(h, w.x, acc.x);
            acc.y = fmaf(h, w.y, acc.y);
            acc.z = fmaf(h, w.z, acc.z);
            acc.w = fmaf(h, w.w, acc.w);
        }
        *(float4*)&sLat[row * 64 + i4] = acc;
    }
    __syncthreads();   // sLat, sBas ready

    for (int o = tid; o < 1024; o += 512) {
        const int m = o >> 6, i = o & 63;
        float acc = 0.f;
        #pragma unroll 8
        for (int v = 0; v < 64; ++v) acc = fmaf(sY[v * 16 + m], sLat[v * 64 + i], acc);
        acc *= QUAD;
        sC[o] = acc;
        wsC[(size_t)b * 1024 + o] = acc;
    }
    if (tid < 9) {
        const int m = tid / 3, c = tid % 3;
        float acc = 0.f;
        for (int v = 0; v < 64; ++v) acc = fmaf(sY[v * 16 + 1 + m], sBas[v * 3 + c], acc);
        sE[tid] = acc * QUAD;
    }
    __syncthreads();   // sC, sE ready

    if (tid < 9) {
        const int m = tid / 3;
        const float e0 = sE[m * 3 + 0], e1 = sE[m * 3 + 1], e2 = sE[m * 3 + 2];
        const float n = sqrtf(e0 * e0 + e1 * e1 + e2 * e2);
        outE[b * 9 + tid] = sE[tid] / fmaxf(n, 1e-6f);
    }
    if (tid < 18) {
        const int which = tid / 9, mc = tid % 9;
        const int m = mc / 3, c = mc % 3;
        float acc = 0.f;
        #pragma unroll 8
        for (int i = 0; i < 64; ++i)
            acc = fmaf(sC[(1 + m) * 64 + i], iw[(2 * i + which) * 3 + c], acc);
        wsAB[b * 18 + tid] = acc;
    }
}

// ============================================================
// Kernel 2a: per-point monomials -> transposed planes; coords + grid-sample.
// grid 1024 x 256 thr; one thread = one point.
// planes stay CACHED (re-read by k_expand); coords/sampled are NT.
// ============================================================
__global__ __launch_bounds__(256) void k_zplanes(
    const float* __restrict__ x, const float* __restrict__ dens,
    const float* __restrict__ ib, float* __restrict__ ws,
    float* __restrict__ out)
{
    const int g = blockIdx.x * 256 + threadIdx.x;    // 0..262143
    const int b = g >> 15, v = g & 32767;

    const float px = x[(size_t)g * 3 + 0];
    const float py = x[(size_t)g * 3 + 1];
    const float pz = x[(size_t)g * 3 + 2];
    const float r2 = px * px + py * py + pz * pz;
    const float r   = sqrtf(r2);
    const float inv = 1.f / fmaxf(r, 1e-6f);
    const float ux = px * inv, uy = py * inv, uz = pz * inv;

    float* zt = ws + WS_ZT + (size_t)b * ZT_PER_B + v;
    const float z1 = 0.48860251f * uy * r;
    const float z2 = 0.48860251f * uz * r;
    const float z3 = 0.48860251f * ux * r;
    zt[0 * 32768] = z1;
    zt[1 * 32768] = z2;
    zt[2 * 32768] = z3;
    zt[3 * 32768] = r2;
    const float r3 = r2 * r;
    zt[4 * 32768]  = 0.59004359f * uy * (3.f * ux * ux - uy * uy) * r3;   // m9
    zt[5 * 32768]  = 2.89061144f * ux * uy * uz * r3;                     // m10
    zt[6 * 32768]  = 0.45704579f * uy * (5.f * uz * uz - 1.f) * r3;       // m11
    zt[7 * 32768]  = 0.37317633f * uz * (5.f * uz * uz - 3.f) * r3;       // m12
    zt[8 * 32768]  = 0.45704579f * ux * (5.f * uz * uz - 1.f) * r3;       // m13
    zt[9 * 32768]  = 1.44530572f * uz * (ux * ux - uy * uy) * r3;         // m14
    zt[10 * 32768] = 0.59004359f * ux * (ux * ux - 3.f * uy * uy) * r3;   // m15
    zt[11 * 32768] = 1.09254843f * ux * uy * r2;                          // m4
    zt[12 * 32768] = 1.09254843f * uy * uz * r2;                          // m5
    zt[13 * 32768] = 0.31539157f * (3.f * uz * uz - 1.f) * r2;            // m6
    zt[14 * 32768] = 1.09254843f * ux * uz * r2;                          // m7
    zt[15 * 32768] = 0.54627421f * (ux * ux - uy * uy) * r2;              // m8

    // coords + grid-sample
    const float* AB = ws + WS_AB + b * 18;
    float pt[3];
    #pragma unroll
    for (int cc = 0; cc < 3; ++cc) {
        float acc = ib[cc];
        acc = fmaf(z1, AB[0 + cc] + r2 * AB[9 + cc], acc);
        acc = fmaf(z2, AB[3 + cc] + r2 * AB[12 + cc], acc);
        acc = fmaf(z3, AB[6 + cc] + r2 * AB[15 + cc], acc);
        pt[cc] = acc;
        nt_store1(out + OFF_COORD + (size_t)g * 3 + cc, acc);
    }

    const float ixf = (pt[0] + 1.f) * 0.5f * 31.f;
    const float iyf = (pt[1] + 1.f) * 0.5f * 31.f;
    const float izf = (pt[2] + 1.f) * 0.5f * 31.f;
    const float x0f = floorf(ixf), y0f = floorf(iyf), z0f = floorf(izf);
    const float wx = ixf - x0f, wy = iyf - y0f, wz = izf - z0f;
    const int x0 = (int)x0f, y0 = (int)y0f, z0 = (int)z0f;
    const float* volb = dens + (size_t)b * 32768;
    float s = 0.f;
    #pragma unroll
    for (int dz = 0; dz < 2; ++dz) {
        const int zi = z0 + dz;
        const float wzz = dz ? wz : 1.f - wz;
        #pragma unroll
        for (int dy = 0; dy < 2; ++dy) {
            const int yi = y0 + dy;
            const float wyy = dy ? wy : 1.f - wy;
            #pragma unroll
            for (int dx = 0; dx < 2; ++dx) {
                const int xi = x0 + dx;
                const float wxx = dx ? wx : 1.f - wx;
                if (zi >= 0 && zi < 32 && yi >= 0 && yi < 32 && xi >= 0 && xi < 32)
                    s += wzz * wyy * wxx * volb[zi * 1024 + yi * 32 + xi];
            }
        }
    }
    nt_store1(out + g, s);
}

// ============================================================
// Kernel 2b: points_code expansion. NT (streaming) stores, wave-aligned
// branches. grid 4096 = (chunk<<3)|b ; 384 thr.
//   tid   0..127 : l0, q=tid&31,       dv=tid>>5        (waves 0-1)
//   tid 128..255 : l1, q=(tid-128)&31, dv=(tid-128)>>5  (waves 2-3)
//   tid 256..319 : l2, q=tid&15,       dv=(tid-256)>>4  (wave 4)
//   tid 320..383 : l3, q=tid&15,       dv=(tid-320)>>4  (wave 5)
// 16 passes p: row = vbase + 4p + dv -> 64 rows/block.
// b = blk&7 : one batch per XCD (L2-resident planes, 2.1 MB/batch).
// ============================================================
__global__ __launch_bounds__(384) void k_expand(
    const float* __restrict__ ws, float* __restrict__ out)
{
    const int blk   = blockIdx.x;
    const int b     = blk & 7;
    const int vbase = (blk >> 3) * 64;
    const int tid   = threadIdx.x;

    const float* C = ws + WS_C + b * 1024;

    if (tid < 128) {
        const int q = tid & 31, dv = tid >> 5;
        const float* zt = ws + WS_ZT + (size_t)b * ZT_PER_B + vbase + dv;
        float* po = out + OFF_CODE + ((size_t)(b * 32768 + vbase + dv)) * 384 + 4 * q;
        const float ca = C[2 * q]     * 0.28209479f;
        const float cb = C[2 * q + 1] * 0.28209479f;
        const float* zr2 = zt + 3 * 32768;
        #pragma unroll 8
        for (int p = 0; p < 16; ++p) {
            const float r2 = zr2[p * 4];
            nt_store4(po + (size_t)p * 1536, ca, ca * r2, cb, cb * r2);
        }
    } else if (tid < 256) {
        const int u = tid - 128, q = u & 31, dv = u >> 5;
        const float* zt = ws + WS_ZT + (size_t)b * ZT_PER_B + vbase + dv;
        float* po = out + OFF_CODE + ((size_t)(b * 32768 + vbase + dv)) * 384 + 128 + 4 * q;
        const float c00 = C[64 + 2 * q],     c01 = C[128 + 2 * q],     c02 = C[192 + 2 * q];
        const float c10 = C[64 + 2 * q + 1], c11 = C[128 + 2 * q + 1], c12 = C[192 + 2 * q + 1];
        const float* za = zt;
        const float* zb = zt + 32768;
        const float* zc = zt + 65536;
        const float* zr2 = zt + 98304;
        #pragma unroll 8
        for (int p = 0; p < 16; ++p) {
            const float a = za[p * 4], bb = zb[p * 4], cc = zc[p * 4], r2 = zr2[p * 4];
            float d0 = c00 * a; d0 = fmaf(c01, bb, d0); d0 = fmaf(c02, cc, d0);
            float d1 = c10 * a; d1 = fmaf(c11, bb, d1); d1 = fmaf(c12, cc, d1);
            nt_store4(po + (size_t)p * 1536, d0, d0 * r2, d1, d1 * r2);
        }
    } else if (tid < 320) {
        const int u = tid - 256, q = u & 15, dv = u >> 4;
        const float* zt = ws + WS_ZT + (size_t)b * ZT_PER_B + vbase + dv;
        const int i0 = 4 * q;
        float* po = out + OFF_CODE + ((size_t)(b * 32768 + vbase + dv)) * 384 + 256 + i0;
        const float4 cf0 = *(const float4*)&C[4 * 64 + i0];
        const float4 cf1 = *(const float4*)&C[5 * 64 + i0];
        const float4 cf2 = *(const float4*)&C[6 * 64 + i0];
        const float4 cf3 = *(const float4*)&C[7 * 64 + i0];
        const float4 cf4 = *(const float4*)&C[8 * 64 + i0];
        const float* p0 = zt + 11 * 32768;
        const float* p1 = zt + 12 * 32768;
        const float* p2 = zt + 13 * 32768;
        const float* p3 = zt + 14 * 32768;
        const float* p4 = zt + 15 * 32768;
        #pragma unroll 4
        for (int p = 0; p < 16; ++p) {
            const float t0 = p0[p * 4], t1 = p1[p * 4], t2 = p2[p * 4];
            const float t3 = p3[p * 4], t4 = p4[p * 4];
            float a0 = cf0.x * t0, a1 = cf0.y * t0, a2 = cf0.z * t0, a3 = cf0.w * t0;
            a0 = fmaf(cf1.x, t1, a0); a1 = fmaf(cf1.y, t1, a1);
            a2 = fmaf(cf1.z, t1, a2); a3 = fmaf(cf1.w, t1, a3);
            a0 = fmaf(cf2.x, t2, a0); a1 = fmaf(cf2.y, t2, a1);
            a2 = fmaf(cf2.z, t2, a2); a3 = fmaf(cf2.w, t2, a3);
            a0 = fmaf(cf3.x, t3, a0); a1 = fmaf(cf3.y, t3, a1);
            a2 = fmaf(cf3.z, t3, a2); a3 = fmaf(cf3.w, t3, a3);
            a0 = fmaf(cf4.x, t4, a0); a1 = fmaf(cf4.y, t4, a1);
            a2 = fmaf(cf4.z, t4, a2); a3 = fmaf(cf4.w, t4, a3);
            nt_store4(po + (size_t)p * 1536, a0, a1, a2, a3);
        }
    } else {
        const int u = tid - 320, q = u & 15, dv = u >> 4;
        const float* zt = ws + WS_ZT + (size_t)b * ZT_PER_B + vbase + dv;
        const int i0 = 4 * q;
        float* po = out + OFF_CODE + ((size_t)(b * 32768 + vbase + dv)) * 384 + 320 + i0;
        const float4 cf0 = *(const float4*)&C[ 9 * 64 + i0];
        const float4 cf1 = *(const float4*)&C[10 * 64 + i0];
        const float4 cf2 = *(const float4*)&C[11 * 64 + i0];
        const float4 cf3 = *(const float4*)&C[12 * 64 + i0];
        const float4 cf4 = *(const float4*)&C[13 * 64 + i0];
        const float4 cf5 = *(const float4*)&C[14 * 64 + i0];
        const float4 cf6 = *(const float4*)&C[15 * 64 + i0];
        const float* p0 = zt + 4 * 32768;
        const float* p1 = zt + 5 * 32768;
        const float* p2 = zt + 6 * 32768;
        const float* p3 = zt + 7 * 32768;
        const float* p4 = zt + 8 * 32768;
        const float* p5 = zt + 9 * 32768;
        const float* p6 = zt + 10 * 32768;
        #pragma unroll 4
        for (int p = 0; p < 16; ++p) {
            const float t0 = p0[p * 4], t1 = p1[p * 4], t2 = p2[p * 4];
            const float t3 = p3[p * 4], t4 = p4[p * 4], t5 = p5[p * 4];
            const float t6 = p6[p * 4];
            float a0 = cf0.x * t0, a1 = cf0.y * t0, a2 = cf0.z * t0, a3 = cf0.w * t0;
            a0 = fmaf(cf1.x, t1, a0); a1 = fmaf(cf1.y, t1, a1);
            a2 = fmaf(cf1.z, t1, a2); a3 = fmaf(cf1.w, t1, a3);
            a0 = fmaf(cf2.x, t2, a0); a1 = fmaf(cf2.y, t2, a1);
            a2 = fmaf(cf2.z, t2, a2); a3 = fmaf(cf2.w, t2, a3);
            a0 = fmaf(cf3.x, t3, a0); a1 = fmaf(cf3.y, t3, a1);
            a2 = fmaf(cf3.z, t3, a2); a3 = fmaf(cf3.w, t3, a3);
            a0 = fmaf(cf4.x, t4, a0); a1 = fmaf(cf4.y, t4, a1);
            a2 = fmaf(cf4.z, t4, a2); a3 = fmaf(cf4.w, t4, a3);
            a0 = fmaf(cf5.x, t5, a0); a1 = fmaf(cf5.y, t5, a1);
            a2 = fmaf(cf5.z, t5, a2); a3 = fmaf(cf5.w, t5, a3);
            a0 = fmaf(cf6.x, t6, a0); a1 = fmaf(cf6.y, t6, a1);
            a2 = fmaf(cf6.z, t6, a2); a3 = fmaf(cf6.w, t6, a3);
            nt_store4(po + (size_t)p * 1536, a0, a1, a2, a3);
        }
    }
}

// ============================================================
// Fallback kernel (round-3 k_points) if ws is too small for the planes.
// ============================================================
__global__ __launch_bounds__(384) void k_points(
    const float* __restrict__ x, const float* __restrict__ dens,
    const float* __restrict__ ws, const float* __restrict__ ib,
    float* __restrict__ out)
{
    __shared__ alignas(16) float sC[16 * 64];
    __shared__ float sAB[18];
    __shared__ alignas(16) float sZ[128 * 20];

    const int blk = blockIdx.x;
    const int b   = blk >> 8;
    const int v0  = (blk & 255) * 128;
    const int tid = threadIdx.x;

    const float* wsC  = ws + WS_C;
    const float* wsAB = ws + WS_AB;

    if (tid < 256) ((float4*)sC)[tid] = ((const float4*)(wsC + (size_t)b * 1024))[tid];
    if (tid < 18) sAB[tid] = wsAB[b * 18 + tid];

    float z1 = 0.f, z2 = 0.f, z3 = 0.f, r2 = 0.f;
    size_t g = 0;
    if (tid < 128) {
        const int v = v0 + tid;
        g = (size_t)b * 32768 + v;
        const float px = x[g * 3 + 0], py = x[g * 3 + 1], pz = x[g * 3 + 2];
        r2 = px * px + py * py + pz * pz;
        const float r   = sqrtf(r2);
        const float inv = 1.f / fmaxf(r, 1e-6f);
        const float ux = px * inv, uy = py * inv, uz = pz * inv;
        float* Z = sZ + tid * 20;
        z1 = 0.48860251f * uy * r;
        z2 = 0.48860251f * uz * r;
        z3 = 0.48860251f * ux * r;
        Z[0] = z1; Z[1] = z2; Z[2] = z3; Z[3] = r2;
        const float r3 = r2 * r;
        Z[4]  = 0.59004359f * uy * (3.f * ux * ux - uy * uy) * r3;
        Z[5]  = 2.89061144f * ux * uy * uz * r3;
        Z[6]  = 0.45704579f * uy * (5.f * uz * uz - 1.f) * r3;
        Z[7]  = 0.37317633f * uz * (5.f * uz * uz - 3.f) * r3;
        Z[8]  = 0.45704579f * ux * (5.f * uz * uz - 1.f) * r3;
        Z[9]  = 1.44530572f * uz * (ux * ux - uy * uy) * r3;
        Z[10] = 0.59004359f * ux * (ux * ux - 3.f * uy * uy) * r3;
        Z[12] = 1.09254843f * ux * uy * r2;
        Z[13] = 1.09254843f * uy * uz * r2;
        Z[14] = 0.31539157f * (3.f * uz * uz - 1.f) * r2;
        Z[15] = 1.09254843f * ux * uz * r2;
        Z[16] = 0.54627421f * (ux * ux - uy * uy) * r2;
    }
    __syncthreads();

    const size_t rowbase = OFF_CODE + ((size_t)b * 32768 + v0) * 384;
    if (tid < 64) {
        const int q = tid & 31, h = tid >> 5;
        const float ca = sC[2 * q]     * 0.28209479f;
        const float cb = sC[2 * q + 1] * 0.28209479f;
        const float* zr = sZ + h * 20 + 3;
        float* po = out + rowbase + (size_t)h * 384 + 4 * q;
        #pragma unroll 8
        for (int vi = 0; vi < 64; ++vi) {
            const float r2v = zr[vi * 40];
            float4 o; o.x = ca; o.y = ca * r2v; o.z = cb; o.w = cb * r2v;
            *(float4*)po = o;
            po += 768;
        }
    } else if (tid < 128) {
        const int u = tid - 64, q = u & 31, h = u >> 5;
        const float c00 = sC[64 + 2 * q],     c01 = sC[128 + 2 * q],     c02 = sC[192 + 2 * q];
        const float c10 = sC[64 + 2 * q + 1], c11 = sC[128 + 2 * q + 1], c12 = sC[192 + 2 * q + 1];
        const float* zr = sZ + h * 20;
        float* po = out + rowbase + (size_t)h * 384 + 128 + 4 * q;
        #pragma unroll 8
        for (int vi = 0; vi < 64; ++vi) {
            const float4 z = *(const float4*)(zr + vi * 40);
            float d0 = c00 * z.x; d0 = fmaf(c01, z.y, d0); d0 = fmaf(c02, z.z, d0);
            float d1 = c10 * z.x; d1 = fmaf(c11, z.y, d1); d1 = fmaf(c12, z.z, d1);
            float4 o; o.x = d0; o.y = d0 * z.w; o.z = d1; o.w = d1 * z.w;
            *(float4*)po = o;
            po += 768;
        }
    } else if (tid < 256) {
        const int q = tid & 15, s = (tid - 128) >> 4;
        const int i0 = 4 * q;
        const float4 cf0 = *(const float4*)&sC[4 * 64 + i0];
        const float4 cf1 = *(const float4*)&sC[5 * 64 + i0];
        const float4 cf2 = *(const float4*)&sC[6 * 64 + i0];
        const float4 cf3 = *(const float4*)&sC[7 * 64 + i0];
        const float4 cf4 = *(const float4*)&sC[8 * 64 + i0];
        const float* zr = sZ + s * 20;
        float* po = out + rowbase + (size_t)s * 384 + 256 + i0;
        #pragma unroll 4
        for (int vi = 0; vi < 16; ++vi) {
            const float4 za = *(const float4*)(zr + vi * 160 + 12);
            const float  zb = zr[vi * 160 + 16];
            float a0 = cf0.x * za.x, a1 = cf0.y * za.x, a2 = cf0.z * za.x, a3 = cf0.w * za.x;
            a0 = fmaf(cf1.x, za.y, a0); a1 = fmaf(cf1.y, za.y, a1);
            a2 = fmaf(cf1.z, za.y, a2); a3 = fmaf(cf1.w, za.y, a3);
            a0 = fmaf(cf2.x, za.z, a0); a1 = fmaf(cf2.y, za.z, a1);
            a2 = fmaf(cf2.z, za.z, a2); a3 = fmaf(cf2.w, za.z, a3);
            a0 = fmaf(cf3.x, za.w, a0); a1 = fmaf(cf3.y, za.w, a1);
            a2 = fmaf(cf3.z, za.w, a2); a3 = fmaf(cf3.w, za.w, a3);
            a0 = fmaf(cf4.x, zb, a0);   a1 = fmaf(cf4.y, zb, a1);
            a2 = fmaf(cf4.z, zb, a2);   a3 = fmaf(cf4.w, zb, a3);
            float4 o; o.x = a0; o.y = a1; o.z = a2; o.w = a3;
            *(float4*)po = o;
            po += 3072;
        }
    } else {
        const int q = tid & 15, s = (tid - 256) >> 4;
        const int i0 = 4 * q;
        const float4 cf0 = *(const float4*)&sC[ 9 * 64 + i0];
        const float4 cf1 = *(const float4*)&sC[10 * 64 + i0];
        const float4 cf2 = *(const float4*)&sC[11 * 64 + i0];
        const float4 cf3 = *(const float4*)&sC[12 * 64 + i0];
        const float4 cf4 = *(const float4*)&sC[13 * 64 + i0];
        const float4 cf5 = *(const float4*)&sC[14 * 64 + i0];
        const float4 cf6 = *(const float4*)&sC[15 * 64 + i0];
        const float* zr = sZ + s * 20;
        float* po = out + rowbase + (size_t)s * 384 + 320 + i0;
        #pragma unroll 4
        for (int vi = 0; vi < 16; ++vi) {
            const float4 za = *(const float4*)(zr + vi * 160 + 4);
            const float2 zb = *(const float2*)(zr + vi * 160 + 8);
            const float  zc = zr[vi * 160 + 10];
            float a0 = cf0.x * za.x, a1 = cf0.y * za.x, a2 = cf0.z * za.x, a3 = cf0.w * za.x;
            a0 = fmaf(cf1.x, za.y, a0); a1 = fmaf(cf1.y, za.y, a1);
            a2 = fmaf(cf1.z, za.y, a2); a3 = fmaf(cf1.w, za.y, a3);
            a0 = fmaf(cf2.x, za.z, a0); a1 = fmaf(cf2.y, za.z, a1);
            a2 = fmaf(cf2.z, za.z, a2); a3 = fmaf(cf2.w, za.z, a3);
            a0 = fmaf(cf3.x, za.w, a0); a1 = fmaf(cf3.y, za.w, a1);
            a2 = fmaf(cf3.z, za.w, a2); a3 = fmaf(cf3.w, za.w, a3);
            a0 = fmaf(cf4.x, zb.x, a0); a1 = fmaf(cf4.y, zb.x, a1);
            a2 = fmaf(cf4.z, zb.x, a2); a3 = fmaf(cf4.w, zb.x, a3);
            a0 = fmaf(cf5.x, zb.y, a0); a1 = fmaf(cf5.y, zb.y, a1);
            a2 = fmaf(cf5.z, zb.y, a2); a3 = fmaf(cf5.w, zb.y, a3);
            a0 = fmaf(cf6.x, zc, a0);   a1 = fmaf(cf6.y, zc, a1);
            a2 = fmaf(cf6.z, zc, a2);   a3 = fmaf(cf6.w, zc, a3);
            float4 o; o.x = a0; o.y = a1; o.z = a2; o.w = a3;
            *(float4*)po = o;
            po += 3072;
        }
    }

    if (tid < 128) {
        const float zr0 = z1, zr1 = z2, zr2 = z3;
        float pt[3];
        #pragma unroll
        for (int cc = 0; cc < 3; ++cc) {
            float acc = ib[cc];
            acc = fmaf(zr0, sAB[0 * 3 + cc] + r2 * sAB[9 + 0 * 3 + cc], acc);
            acc = fmaf(zr1, sAB[1 * 3 + cc] + r2 * sAB[9 + 1 * 3 + cc], acc);
            acc = fmaf(zr2, sAB[2 * 3 + cc] + r2 * sAB[9 + 2 * 3 + cc], acc);
            pt[cc] = acc;
            out[OFF_COORD + g * 3 + cc] = acc;
        }

        const float ix = (pt[0] + 1.f) * 0.5f * 31.f;
        const float iy = (pt[1] + 1.f) * 0.5f * 31.f;
        const float iz = (pt[2] + 1.f) * 0.5f * 31.f;
        const float x0f = floorf(ix), y0f = floorf(iy), z0f = floorf(iz);
        const float wx = ix - x0f, wy = iy - y0f, wz = iz - z0f;
        const int x0 = (int)x0f, y0 = (int)y0f, z0 = (int)z0f;
        const float* volb = dens + (size_t)b * 32768;
        float s = 0.f;
        #pragma unroll
        for (int dz = 0; dz < 2; ++dz) {
            const int zi = z0 + dz;
            const float wzz = dz ? wz : 1.f - wz;
            #pragma unroll
            for (int dy = 0; dy < 2; ++dy) {
                const int yi = y0 + dy;
                const float wyy = dy ? wy : 1.f - wy;
                #pragma unroll
                for (int dx = 0; dx < 2; ++dx) {
                    const int xi = x0 + dx;
                    const float wxx = dx ? wx : 1.f - wx;
                    if (zi >= 0 && zi < 32 && yi >= 0 && yi < 32 && xi >= 0 && xi < 32)
                        s += wzz * wyy * wxx * volb[zi * 1024 + yi * 32 + xi];
                }
            }
        }
        out[g] = s;
    }
}

// ============================================================
extern "C" void kernel_launch(void* const* d_in, const int* in_sizes, int n_in,
                              void* d_out, int out_size, void* d_ws, size_t ws_size,
                              hipStream_t stream) {
    const float* x    = (const float*)d_in[0];
    const float* dens = (const float*)d_in[1];
    const float* F    = (const float*)d_in[2];
    const float* S2   = (const float*)d_in[3];
    const float* bw1  = (const float*)d_in[4];
    const float* bb1  = (const float*)d_in[5];
    const float* bw2  = (const float*)d_in[6];
    const float* bb2  = (const float*)d_in[7];
    const float* cw1  = (const float*)d_in[8];
    const float* cb1  = (const float*)d_in[9];
    const float* cw2  = (const float*)d_in[10];
    const float* cb2  = (const float*)d_in[11];
    const float* iw   = (const float*)d_in[12];
    const float* ib   = (const float*)d_in[13];
    float* out = (float*)d_out;
    float* ws  = (float*)d_ws;

    k_hidden<<<64, 384, 0, stream>>>(F, bw1, bb1, cw1, cb1, ws);
    k_coeffs<<<8,  512, 0, stream>>>(ws, S2, bw2, bb2, cw2, cb2, iw, ws, out + OFF_E);

    const size_t ws_needed = (size_t)(WS_ZT + 8 * ZT_PER_B) * sizeof(float);
    if (ws_size >= ws_needed) {
        k_zplanes<<<1024, 256, 0, stream>>>(x, dens, ib, ws, out);
        k_expand<<<4096,  384, 0, stream>>>(ws, out);
    } else {
        k_points<<<2048,  384, 0, stream>>>(x, dens, ws, ib, out);
    }
}

// Round 6
// 503.592 us; speedup vs baseline: 1.1549x; 1.1549x over previous
//
#include <hip/hip_runtime.h>
#include <math.h>

// ---- problem constants ----
// B=8, H=W=D=32, V=32768 per batch, S=64
// outputs (flat, in return order):
//   sampled [8,32,32,32]         -> 262144  @ 0
//   E       [8,3,3]              -> 72      @ 262144
//   coords  [8,32,32,32,3]       -> 786432  @ 262216
//   points_code [8,32768,384]    -> 100663296 @ 1048648
#define OFF_E     262144
#define OFF_COORD 262216
#define OFF_CODE  1048648

#define QUAD 0.19634954084936207f   // 4*pi/64

// ---- ws layout (floats) ----
#define WS_H1 0
#define WS_H2 32768
#define WS_C  98304
#define WS_AB 106496

typedef float f4v __attribute__((ext_vector_type(4)));

// ============================================================
// Kernel 1a: hidden layers.  grid 64 = 8 batches x 8 row-groups, 384 thr
// ============================================================
__global__ __launch_bounds__(384) void k_hidden(
    const float* __restrict__ F,
    const float* __restrict__ bw1, const float* __restrict__ bb1,
    const float* __restrict__ cw1, const float* __restrict__ cb1,
    float* __restrict__ ws)
{
    __shared__ float sF[8 * 257];   // +1 pad: rows hit distinct banks
    const int blk = blockIdx.x;
    const int b   = blk >> 3;
    const int r0  = (blk & 7) * 8;
    const int tid = threadIdx.x;

    float* wsH1 = ws + WS_H1;
    float* wsH2 = ws + WS_H2;

    const float* Fb = F + ((size_t)b * 64 + r0) * 256;
    for (int i = tid; i < 2048; i += 384) sF[(i >> 8) * 257 + (i & 255)] = Fb[i];
    __syncthreads();

    if (tid < 128) {
        const int row = tid >> 4, k4 = (tid & 15) * 4;
        const float* fr = sF + row * 257;
        float4 acc = *(const float4*)&bb1[k4];
        #pragma unroll 4
        for (int j = 0; j < 256; ++j) {
            const float  f = fr[j];
            const float4 w = *(const float4*)&bw1[j * 64 + k4];
            acc.x = fmaf(f, w.x, acc.x);
            acc.y = fmaf(f, w.y, acc.y);
            acc.z = fmaf(f, w.z, acc.z);
            acc.w = fmaf(f, w.w, acc.w);
        }
        acc.x = fmaxf(acc.x, 0.f); acc.y = fmaxf(acc.y, 0.f);
        acc.z = fmaxf(acc.z, 0.f); acc.w = fmaxf(acc.w, 0.f);
        *(float4*)&wsH1[((size_t)b * 64 + r0 + row) * 64 + k4] = acc;
    } else {
        const int tt  = tid - 128;
        const int row = tt >> 5, k4 = (tt & 31) * 4;
        const float* fr = sF + row * 257;
        float4 acc = *(const float4*)&cb1[k4];
        #pragma unroll 4
        for (int j = 0; j < 256; ++j) {
            const float  f = fr[j];
            const float4 w = *(const float4*)&cw1[j * 128 + k4];
            acc.x = fmaf(f, w.x, acc.x);
            acc.y = fmaf(f, w.y, acc.y);
            acc.z = fmaf(f, w.z, acc.z);
            acc.w = fmaf(f, w.w, acc.w);
        }
        acc.x = fmaxf(acc.x, 0.f); acc.y = fmaxf(acc.y, 0.f);
        acc.z = fmaxf(acc.z, 0.f); acc.w = fmaxf(acc.w, 0.f);
        *(float4*)&wsH2[((size_t)b * 64 + r0 + row) * 128 + k4] = acc;
    }
}

// ============================================================
// Kernel 1b: latent, basis, Y(S2), coeffs, E, A/B.  grid 8, 512 thr
// ============================================================
__global__ __launch_bounds__(512) void k_coeffs(
    const float* __restrict__ ws_in,
    const float* __restrict__ S2,
    const float* __restrict__ bw2, const float* __restrict__ bb2,
    const float* __restrict__ cw2, const float* __restrict__ cb2,
    const float* __restrict__ iw,
    float* __restrict__ ws_out, float* __restrict__ outE)
{
    __shared__ float sH2[64 * 129];             // padded stride
    __shared__ alignas(16) float sLat[64 * 64];
    __shared__ float sY[64 * 16];
    __shared__ float sBas[64 * 3];
    __shared__ float sC[16 * 64];
    __shared__ float sE[9];

    const int b = blockIdx.x, tid = threadIdx.x;
    const float* wsH1 = ws_in + WS_H1;
    const float* wsH2 = ws_in + WS_H2;
    float* wsC  = ws_out + WS_C;
    float* wsAB = ws_out + WS_AB;

    const float* H2b = wsH2 + (size_t)b * 8192;
    for (int i = tid; i < 8192; i += 512) sH2[(i >> 7) * 129 + (i & 127)] = H2b[i];

    if (tid < 64) {
        const float x = S2[tid * 3 + 0], y = S2[tid * 3 + 1], z = S2[tid * 3 + 2];
        float* Yv = sY + tid * 16;
        Yv[0]  = 0.28209479f;
        Yv[1]  = 0.48860251f * y;
        Yv[2]  = 0.48860251f * z;
        Yv[3]  = 0.48860251f * x;
        Yv[4]  = 1.09254843f * x * y;
        Yv[5]  = 1.09254843f * y * z;
        Yv[6]  = 0.31539157f * (3.f * z * z - 1.f);
        Yv[7]  = 1.09254843f * x * z;
        Yv[8]  = 0.54627421f * (x * x - y * y);
        Yv[9]  = 0.59004359f * y * (3.f * x * x - y * y);
        Yv[10] = 2.89061144f * x * y * z;
        Yv[11] = 0.45704579f * y * (5.f * z * z - 1.f);
        Yv[12] = 0.37317633f * z * (5.f * z * z - 3.f);
        Yv[13] = 0.45704579f * x * (5.f * z * z - 1.f);
        Yv[14] = 1.44530572f * z * (x * x - y * y);
        Yv[15] = 0.59004359f * x * (x * x - 3.f * y * y);
    }

    float breg = 0.f;
    if (tid < 192) {
        const int v = tid / 3, c = tid % 3;
        const float* h1 = wsH1 + ((size_t)b * 64 + v) * 64;
        float acc = bb2[c];
        #pragma unroll 8
        for (int k = 0; k < 64; ++k) acc = fmaf(h1[k], bw2[k * 3 + c], acc);
        breg = acc;
    }
    __syncthreads();   // sH2, sY ready

    if (tid < 192) sBas[tid] = breg;

    for (int t = tid; t < 1024; t += 512) {
        const int row = t >> 4, i4 = (t & 15) * 4;
        const float* h2 = sH2 + row * 129;
        float4 acc = *(const float4*)&cb2[i4];
        #pragma unroll 4
        for (int k = 0; k < 128; ++k) {
            const float  h = h2[k];
            const float4 w = *(const float4*)&cw2[k * 64 + i4];
            acc.x = fmaf(h, w.x, acc.x);
            acc.y = fmaf(h, w.y, acc.y);
            acc.z = fmaf(h, w.z, acc.z);
            acc.w = fmaf(h, w.w, acc.w);
        }
        *(float4*)&sLat[row * 64 + i4] = acc;
    }
    __syncthreads();   // sLat, sBas ready

    for (int o = tid; o < 1024; o += 512) {
        const int m = o >> 6, i = o & 63;
        float acc = 0.f;
        #pragma unroll 8
        for (int v = 0; v < 64; ++v) acc = fmaf(sY[v * 16 + m], sLat[v * 64 + i], acc);
        acc *= QUAD;
        sC[o] = acc;
        wsC[(size_t)b * 1024 + o] = acc;
    }
    if (tid < 9) {
        const int m = tid / 3, c = tid % 3;
        float acc = 0.f;
        for (int v = 0; v < 64; ++v) acc = fmaf(sY[v * 16 + 1 + m], sBas[v * 3 + c], acc);
        sE[tid] = acc * QUAD;
    }
    __syncthreads();   // sC, sE ready

    if (tid < 9) {
        const int m = tid / 3;
        const float e0 = sE[m * 3 + 0], e1 = sE[m * 3 + 1], e2 = sE[m * 3 + 2];
        const float n = sqrtf(e0 * e0 + e1 * e1 + e2 * e2);
        outE[b * 9 + tid] = sE[tid] / fmaxf(n, 1e-6f);
    }
    if (tid < 18) {
        const int which = tid / 9, mc = tid % 9;
        const int m = mc / 3, c = mc % 3;
        float acc = 0.f;
        #pragma unroll 8
        for (int i = 0; i < 64; ++i)
            acc = fmaf(sC[(1 + m) * 64 + i], iw[(2 * i + which) * 3 + c], acc);
        wsAB[b * 18 + tid] = acc;
    }
}

// ============================================================
// Kernel 2: fused monomials + coords + grid-sample + points_code.
// grid 4096 = (grp<<3)|b, b=blk&7 (batch per XCD); 384 thr (6 waves);
// 64 rows per block.
//
// STORE MAP (the point of this round): flat-index the block's 64x384-float
// output tile.  pass p, wave w, lane l owns floats p*1536 + w*256 + 4l.
// -> every global_store_dwordx4 is ONE contiguous, lane-ordered 1024-B run
//    (previous rounds: 2x512B or 4x256B segments per instruction).
// Lane's (row-offset rw, channel-quad c) is pass-invariant; per-lane math is
// a branchless zero-padded dot-7 of constant coeffs cf[7] (f4v, one per
// monomial slot) against a per-row per-class T vector in LDS:
//   class l0 (c<128):   T=[1, r2, 0..]            slots  0..7
//   class l1 (c<256):   T=[z1,z2,z3,z1r2,z2r2,z3r2,0,0] slots 8..15
//   class l2 (c<320):   T=[P2m4..m8 (*r2), 0,0,0] slots 16..23
//   class l3 (c>=320):  T=[P3m9..m15 (*r3), 0]    slots 24..31
// ============================================================
__global__ __launch_bounds__(384) void k_code(
    const float* __restrict__ x, const float* __restrict__ dens,
    const float* __restrict__ ws, const float* __restrict__ ib,
    float* __restrict__ out)
{
    __shared__ alignas(16) float sC[1024];
    __shared__ alignas(16) float sT[64 * 32];   // 8 KB

    const int blk   = blockIdx.x;
    const int b     = blk & 7;
    const int vbase = (blk >> 3) * 64;
    const int tid   = threadIdx.x;

    if (tid < 256)
        ((f4v*)sC)[tid] = ((const f4v*)(ws + WS_C + b * 1024))[tid];

    // ---- prologue (wave 0): monomials -> sT, coords, grid-sample ----
    if (tid < 64) {
        const int g = b * 32768 + vbase + tid;
        const float px = x[(size_t)g * 3 + 0];
        const float py = x[(size_t)g * 3 + 1];
        const float pz = x[(size_t)g * 3 + 2];
        const float r2 = px * px + py * py + pz * pz;
        const float r   = sqrtf(r2);
        const float inv = 1.f / fmaxf(r, 1e-6f);
        const float ux = px * inv, uy = py * inv, uz = pz * inv;
        const float r3 = r2 * r;

        const float z1 = 0.48860251f * uy * r;
        const float z2 = 0.48860251f * uz * r;
        const float z3 = 0.48860251f * ux * r;

        float* T = sT + tid * 32;
        T[0]  = 1.f;  T[1] = r2;  T[2] = 0.f; T[3] = 0.f;
        T[4]  = 0.f;  T[5] = 0.f; T[6] = 0.f; T[7] = 0.f;
        T[8]  = z1;   T[9] = z2;  T[10] = z3;
        T[11] = z1 * r2; T[12] = z2 * r2; T[13] = z3 * r2;
        T[14] = 0.f;  T[15] = 0.f;
        T[16] = 1.09254843f * ux * uy * r2;                          // m4
        T[17] = 1.09254843f * uy * uz * r2;                          // m5
        T[18] = 0.31539157f * (3.f * uz * uz - 1.f) * r2;            // m6
        T[19] = 1.09254843f * ux * uz * r2;                          // m7
        T[20] = 0.54627421f * (ux * ux - uy * uy) * r2;              // m8
        T[21] = 0.f; T[22] = 0.f; T[23] = 0.f;
        T[24] = 0.59004359f * uy * (3.f * ux * ux - uy * uy) * r3;   // m9
        T[25] = 2.89061144f * ux * uy * uz * r3;                     // m10
        T[26] = 0.45704579f * uy * (5.f * uz * uz - 1.f) * r3;       // m11
        T[27] = 0.37317633f * uz * (5.f * uz * uz - 3.f) * r3;       // m12
        T[28] = 0.45704579f * ux * (5.f * uz * uz - 1.f) * r3;       // m13
        T[29] = 1.44530572f * uz * (ux * ux - uy * uy) * r3;         // m14
        T[30] = 0.59004359f * ux * (ux * ux - 3.f * uy * uy) * r3;   // m15
        T[31] = 0.f;

        // coords + grid-sample
        const float* AB = ws + WS_AB + b * 18;
        float pt[3];
        #pragma unroll
        for (int cc = 0; cc < 3; ++cc) {
            float acc = ib[cc];
            acc = fmaf(z1, AB[0 + cc] + r2 * AB[9  + cc], acc);
            acc = fmaf(z2, AB[3 + cc] + r2 * AB[12 + cc], acc);
            acc = fmaf(z3, AB[6 + cc] + r2 * AB[15 + cc], acc);
            pt[cc] = acc;
            out[OFF_COORD + (size_t)g * 3 + cc] = acc;
        }
        const float ixf = (pt[0] + 1.f) * 0.5f * 31.f;
        const float iyf = (pt[1] + 1.f) * 0.5f * 31.f;
        const float izf = (pt[2] + 1.f) * 0.5f * 31.f;
        const float x0f = floorf(ixf), y0f = floorf(iyf), z0f = floorf(izf);
        const float wx = ixf - x0f, wy = iyf - y0f, wz = izf - z0f;
        const int x0 = (int)x0f, y0 = (int)y0f, z0 = (int)z0f;
        const float* volb = dens + (size_t)b * 32768;
        float s = 0.f;
        #pragma unroll
        for (int dz = 0; dz < 2; ++dz) {
            const int zi = z0 + dz;
            const float wzz = dz ? wz : 1.f - wz;
            #pragma unroll
            for (int dy = 0; dy < 2; ++dy) {
                const int yi = y0 + dy;
                const float wyy = dy ? wy : 1.f - wy;
                #pragma unroll
                for (int dx = 0; dx < 2; ++dx) {
                    const int xi = x0 + dx;
                    const float wxx = dx ? wx : 1.f - wx;
                    if (zi >= 0 && zi < 32 && yi >= 0 && yi < 32 && xi >= 0 && xi < 32)
                        s += wzz * wyy * wxx * volb[zi * 1024 + yi * 32 + xi];
                }
            }
        }
        out[g] = s;
    }
    __syncthreads();

    // ---- per-lane constant setup ----
    const int w  = tid >> 6, l = tid & 63;
    const int g0 = w * 256 + 4 * l;          // flat float index within a 4-row stripe
    const int rw = g0 / 384;                 // 0..3: row offset within stripe
    const int c  = g0 - rw * 384;            // channel-quad base (multiple of 4)

    f4v cf0 = {0.f,0.f,0.f,0.f}, cf1 = cf0, cf2 = cf0, cf3 = cf0;
    f4v cf4 = cf0, cf5 = cf0, cf6 = cf0;
    int tb;
    if (c < 128) {
        const int i0 = c >> 1;
        const float ca = sC[i0]     * 0.28209479f;
        const float cb = sC[i0 + 1] * 0.28209479f;
        cf0 = (f4v){ca, 0.f, cb, 0.f};
        cf1 = (f4v){0.f, ca, 0.f, cb};
        tb = 0;
    } else if (c < 256) {
        const int u = (c - 128) >> 1;
        const float a0 = sC[64 + u],     a1 = sC[128 + u],     a2 = sC[192 + u];
        const float b0 = sC[64 + u + 1], b1 = sC[128 + u + 1], b2 = sC[192 + u + 1];
        cf0 = (f4v){a0, 0.f, b0, 0.f};
        cf1 = (f4v){a1, 0.f, b1, 0.f};
        cf2 = (f4v){a2, 0.f, b2, 0.f};
        cf3 = (f4v){0.f, a0, 0.f, b0};
        cf4 = (f4v){0.f, a1, 0.f, b1};
        cf5 = (f4v){0.f, a2, 0.f, b2};
        tb = 8;
    } else if (c < 320) {
        const int i0 = c - 256;
        cf0 = *(const f4v*)&sC[4 * 64 + i0];
        cf1 = *(const f4v*)&sC[5 * 64 + i0];
        cf2 = *(const f4v*)&sC[6 * 64 + i0];
        cf3 = *(const f4v*)&sC[7 * 64 + i0];
        cf4 = *(const f4v*)&sC[8 * 64 + i0];
        tb = 16;
    } else {
        const int i0 = c - 320;
        cf0 = *(const f4v*)&sC[ 9 * 64 + i0];
        cf1 = *(const f4v*)&sC[10 * 64 + i0];
        cf2 = *(const f4v*)&sC[11 * 64 + i0];
        cf3 = *(const f4v*)&sC[12 * 64 + i0];
        cf4 = *(const f4v*)&sC[13 * 64 + i0];
        cf5 = *(const f4v*)&sC[14 * 64 + i0];
        cf6 = *(const f4v*)&sC[15 * 64 + i0];
        tb = 24;
    }

    const float* Tb = sT + tb;
    float* po = out + OFF_CODE + ((size_t)(b * 32768 + vbase)) * 384 + g0;

    // ---- 16 passes: 2 LDS b128 broadcast reads + 28 FMA + ONE contiguous
    //      1-KB wave store per pass ----
    #pragma unroll 4
    for (int p = 0; p < 16; ++p) {
        const int ro = (4 * p + rw) * 32;
        const f4v ta = *(const f4v*)(Tb + ro);
        const f4v tb4 = *(const f4v*)(Tb + ro + 4);
        f4v acc = cf0 * ta.x;
        acc += cf1 * ta.y;
        acc += cf2 * ta.z;
        acc += cf3 * ta.w;
        acc += cf4 * tb4.x;
        acc += cf5 * tb4.y;
        acc += cf6 * tb4.z;
        *(f4v*)(po + p * 1536) = acc;
    }
}

// ============================================================
extern "C" void kernel_launch(void* const* d_in, const int* in_sizes, int n_in,
                              void* d_out, int out_size, void* d_ws, size_t ws_size,
                              hipStream_t stream) {
    const float* x    = (const float*)d_in[0];
    const float* dens = (const float*)d_in[1];
    const float* F    = (const float*)d_in[2];
    const float* S2   = (const float*)d_in[3];
    const float* bw1  = (const float*)d_in[4];
    const float* bb1  = (const float*)d_in[5];
    const float* bw2  = (const float*)d_in[6];
    const float* bb2  = (const float*)d_in[7];
    const float* cw1  = (const float*)d_in[8];
    const float* cb1  = (const float*)d_in[9];
    const float* cw2  = (const float*)d_in[10];
    const float* cb2  = (const float*)d_in[11];
    const float* iw   = (const float*)d_in[12];
    const float* ib   = (const float*)d_in[13];
    float* out = (float*)d_out;
    float* ws  = (float*)d_ws;

    k_hidden<<<64,   384, 0, stream>>>(F, bw1, bb1, cw1, cb1, ws);
    k_coeffs<<<8,    512, 0, stream>>>(ws, S2, bw2, bb2, cw2, cb2, iw, ws, out + OFF_E);
    k_code<<<4096,   384, 0, stream>>>(x, dens, ws, ib, out);
}

// Round 7
// 499.587 us; speedup vs baseline: 1.1641x; 1.0080x over previous
//
#include <hip/hip_runtime.h>
#include <math.h>

// ---- problem constants ----
// B=8, H=W=D=32, V=32768 per batch, S=64
// outputs (flat, in return order):
//   sampled [8,32,32,32]         -> 262144  @ 0
//   E       [8,3,3]              -> 72      @ 262144
//   coords  [8,32,32,32,3]       -> 786432  @ 262216
//   points_code [8,32768,384]    -> 100663296 @ 1048648
#define OFF_E     262144
#define OFF_COORD 262216
#define OFF_CODE  1048648

#define QUAD 0.19634954084936207f   // 4*pi/64

// ---- ws layout (floats) ----
#define WS_H1 0
#define WS_H2 32768
#define WS_C  98304
#define WS_AB 106496

typedef float f4v __attribute__((ext_vector_type(4)));

// ============================================================
// Kernel 1a: hidden layers.  grid 64 = 8 batches x 8 row-groups, 384 thr
// ============================================================
__global__ __launch_bounds__(384) void k_hidden(
    const float* __restrict__ F,
    const float* __restrict__ bw1, const float* __restrict__ bb1,
    const float* __restrict__ cw1, const float* __restrict__ cb1,
    float* __restrict__ ws)
{
    __shared__ float sF[8 * 257];   // +1 pad: rows hit distinct banks
    const int blk = blockIdx.x;
    const int b   = blk >> 3;
    const int r0  = (blk & 7) * 8;
    const int tid = threadIdx.x;

    float* wsH1 = ws + WS_H1;
    float* wsH2 = ws + WS_H2;

    const float* Fb = F + ((size_t)b * 64 + r0) * 256;
    for (int i = tid; i < 2048; i += 384) sF[(i >> 8) * 257 + (i & 255)] = Fb[i];
    __syncthreads();

    if (tid < 128) {
        const int row = tid >> 4, k4 = (tid & 15) * 4;
        const float* fr = sF + row * 257;
        float4 acc = *(const float4*)&bb1[k4];
        #pragma unroll 4
        for (int j = 0; j < 256; ++j) {
            const float  f = fr[j];
            const float4 w = *(const float4*)&bw1[j * 64 + k4];
            acc.x = fmaf(f, w.x, acc.x);
            acc.y = fmaf(f, w.y, acc.y);
            acc.z = fmaf(f, w.z, acc.z);
            acc.w = fmaf(f, w.w, acc.w);
        }
        acc.x = fmaxf(acc.x, 0.f); acc.y = fmaxf(acc.y, 0.f);
        acc.z = fmaxf(acc.z, 0.f); acc.w = fmaxf(acc.w, 0.f);
        *(float4*)&wsH1[((size_t)b * 64 + r0 + row) * 64 + k4] = acc;
    } else {
        const int tt  = tid - 128;
        const int row = tt >> 5, k4 = (tt & 31) * 4;
        const float* fr = sF + row * 257;
        float4 acc = *(const float4*)&cb1[k4];
        #pragma unroll 4
        for (int j = 0; j < 256; ++j) {
            const float  f = fr[j];
            const float4 w = *(const float4*)&cw1[j * 128 + k4];
            acc.x = fmaf(f, w.x, acc.x);
            acc.y = fmaf(f, w.y, acc.y);
            acc.z = fmaf(f, w.z, acc.z);
            acc.w = fmaf(f, w.w, acc.w);
        }
        acc.x = fmaxf(acc.x, 0.f); acc.y = fmaxf(acc.y, 0.f);
        acc.z = fmaxf(acc.z, 0.f); acc.w = fmaxf(acc.w, 0.f);
        *(float4*)&wsH2[((size_t)b * 64 + r0 + row) * 128 + k4] = acc;
    }
}

// ============================================================
// Kernel 1b: latent, basis, Y(S2), coeffs, E, A/B.  grid 8, 512 thr
// ============================================================
__global__ __launch_bounds__(512) void k_coeffs(
    const float* __restrict__ ws_in,
    const float* __restrict__ S2,
    const float* __restrict__ bw2, const float* __restrict__ bb2,
    const float* __restrict__ cw2, const float* __restrict__ cb2,
    const float* __restrict__ iw,
    float* __restrict__ ws_out, float* __restrict__ outE)
{
    __shared__ float sH2[64 * 129];             // padded stride
    __shared__ alignas(16) float sLat[64 * 64];
    __shared__ float sY[64 * 16];
    __shared__ float sBas[64 * 3];
    __shared__ float sC[16 * 64];
    __shared__ float sE[9];

    const int b = blockIdx.x, tid = threadIdx.x;
    const float* wsH1 = ws_in + WS_H1;
    const float* wsH2 = ws_in + WS_H2;
    float* wsC  = ws_out + WS_C;
    float* wsAB = ws_out + WS_AB;

    const float* H2b = wsH2 + (size_t)b * 8192;
    for (int i = tid; i < 8192; i += 512) sH2[(i >> 7) * 129 + (i & 127)] = H2b[i];

    if (tid < 64) {
        const float x = S2[tid * 3 + 0], y = S2[tid * 3 + 1], z = S2[tid * 3 + 2];
        float* Yv = sY + tid * 16;
        Yv[0]  = 0.28209479f;
        Yv[1]  = 0.48860251f * y;
        Yv[2]  = 0.48860251f * z;
        Yv[3]  = 0.48860251f * x;
        Yv[4]  = 1.09254843f * x * y;
        Yv[5]  = 1.09254843f * y * z;
        Yv[6]  = 0.31539157f * (3.f * z * z - 1.f);
        Yv[7]  = 1.09254843f * x * z;
        Yv[8]  = 0.54627421f * (x * x - y * y);
        Yv[9]  = 0.59004359f * y * (3.f * x * x - y * y);
        Yv[10] = 2.89061144f * x * y * z;
        Yv[11] = 0.45704579f * y * (5.f * z * z - 1.f);
        Yv[12] = 0.37317633f * z * (5.f * z * z - 3.f);
        Yv[13] = 0.45704579f * x * (5.f * z * z - 1.f);
        Yv[14] = 1.44530572f * z * (x * x - y * y);
        Yv[15] = 0.59004359f * x * (x * x - 3.f * y * y);
    }

    float breg = 0.f;
    if (tid < 192) {
        const int v = tid / 3, c = tid % 3;
        const float* h1 = wsH1 + ((size_t)b * 64 + v) * 64;
        float acc = bb2[c];
        #pragma unroll 8
        for (int k = 0; k < 64; ++k) acc = fmaf(h1[k], bw2[k * 3 + c], acc);
        breg = acc;
    }
    __syncthreads();   // sH2, sY ready

    if (tid < 192) sBas[tid] = breg;

    for (int t = tid; t < 1024; t += 512) {
        const int row = t >> 4, i4 = (t & 15) * 4;
        const float* h2 = sH2 + row * 129;
        float4 acc = *(const float4*)&cb2[i4];
        #pragma unroll 4
        for (int k = 0; k < 128; ++k) {
            const float  h = h2[k];
            const float4 w = *(const float4*)&cw2[k * 64 + i4];
            acc.x = fmaf(h, w.x, acc.x);
            acc.y = fmaf(h, w.y, acc.y);
            acc.z = fmaf(h, w.z, acc.z);
            acc.w = fmaf(h, w.w, acc.w);
        }
        *(float4*)&sLat[row * 64 + i4] = acc;
    }
    __syncthreads();   // sLat, sBas ready

    for (int o = tid; o < 1024; o += 512) {
        const int m = o >> 6, i = o & 63;
        float acc = 0.f;
        #pragma unroll 8
        for (int v = 0; v < 64; ++v) acc = fmaf(sY[v * 16 + m], sLat[v * 64 + i], acc);
        acc *= QUAD;
        sC[o] = acc;
        wsC[(size_t)b * 1024 + o] = acc;
    }
    if (tid < 9) {
        const int m = tid / 3, c = tid % 3;
        float acc = 0.f;
        for (int v = 0; v < 64; ++v) acc = fmaf(sY[v * 16 + 1 + m], sBas[v * 3 + c], acc);
        sE[tid] = acc * QUAD;
    }
    __syncthreads();   // sC, sE ready

    if (tid < 9) {
        const int m = tid / 3;
        const float e0 = sE[m * 3 + 0], e1 = sE[m * 3 + 1], e2 = sE[m * 3 + 2];
        const float n = sqrtf(e0 * e0 + e1 * e1 + e2 * e2);
        outE[b * 9 + tid] = sE[tid] / fmaxf(n, 1e-6f);
    }
    if (tid < 18) {
        const int which = tid / 9, mc = tid % 9;
        const int m = mc / 3, c = mc % 3;
        float acc = 0.f;
        #pragma unroll 8
        for (int i = 0; i < 64; ++i)
            acc = fmaf(sC[(1 + m) * 64 + i], iw[(2 * i + which) * 3 + c], acc);
        wsAB[b * 18 + tid] = acc;
    }
}

// ============================================================
// Kernel 2: fused monomials + coords + grid-sample + points_code.
// Same structure as round 6 (1-KB contiguous lane-ordered wave stores),
// EXCEPT: DIAGNOSTIC double-store. Per 4-pass chunk, the 4 f4v values are
// computed ONCE into registers, then stored TWICE (identical values ->
// idempotent, output unchanged; memory clobber defeats dead-store elim).
// Marginal time = pure store-drain margin; pushes k_code into the top-5
// so we finally get its WRITE/FETCH/VALU/Occupancy counters.
// ============================================================
__global__ __launch_bounds__(384) void k_code(
    const float* __restrict__ x, const float* __restrict__ dens,
    const float* __restrict__ ws, const float* __restrict__ ib,
    float* __restrict__ out)
{
    __shared__ alignas(16) float sC[1024];
    __shared__ alignas(16) float sT[64 * 32];   // 8 KB

    const int blk   = blockIdx.x;
    const int b     = blk & 7;
    const int vbase = (blk >> 3) * 64;
    const int tid   = threadIdx.x;

    if (tid < 256)
        ((f4v*)sC)[tid] = ((const f4v*)(ws + WS_C + b * 1024))[tid];

    // ---- prologue (wave 0): monomials -> sT, coords, grid-sample ----
    if (tid < 64) {
        const int g = b * 32768 + vbase + tid;
        const float px = x[(size_t)g * 3 + 0];
        const float py = x[(size_t)g * 3 + 1];
        const float pz = x[(size_t)g * 3 + 2];
        const float r2 = px * px + py * py + pz * pz;
        const float r   = sqrtf(r2);
        const float inv = 1.f / fmaxf(r, 1e-6f);
        const float ux = px * inv, uy = py * inv, uz = pz * inv;
        const float r3 = r2 * r;

        const float z1 = 0.48860251f * uy * r;
        const float z2 = 0.48860251f * uz * r;
        const float z3 = 0.48860251f * ux * r;

        float* T = sT + tid * 32;
        T[0]  = 1.f;  T[1] = r2;  T[2] = 0.f; T[3] = 0.f;
        T[4]  = 0.f;  T[5] = 0.f; T[6] = 0.f; T[7] = 0.f;
        T[8]  = z1;   T[9] = z2;  T[10] = z3;
        T[11] = z1 * r2; T[12] = z2 * r2; T[13] = z3 * r2;
        T[14] = 0.f;  T[15] = 0.f;
        T[16] = 1.09254843f * ux * uy * r2;                          // m4
        T[17] = 1.09254843f * uy * uz * r2;                          // m5
        T[18] = 0.31539157f * (3.f * uz * uz - 1.f) * r2;            // m6
        T[19] = 1.09254843f * ux * uz * r2;                          // m7
        T[20] = 0.54627421f * (ux * ux - uy * uy) * r2;              // m8
        T[21] = 0.f; T[22] = 0.f; T[23] = 0.f;
        T[24] = 0.59004359f * uy * (3.f * ux * ux - uy * uy) * r3;   // m9
        T[25] = 2.89061144f * ux * uy * uz * r3;                     // m10
        T[26] = 0.45704579f * uy * (5.f * uz * uz - 1.f) * r3;       // m11
        T[27] = 0.37317633f * uz * (5.f * uz * uz - 3.f) * r3;       // m12
        T[28] = 0.45704579f * ux * (5.f * uz * uz - 1.f) * r3;       // m13
        T[29] = 1.44530572f * uz * (ux * ux - uy * uy) * r3;         // m14
        T[30] = 0.59004359f * ux * (ux * ux - 3.f * uy * uy) * r3;   // m15
        T[31] = 0.f;

        // coords + grid-sample
        const float* AB = ws + WS_AB + b * 18;
        float pt[3];
        #pragma unroll
        for (int cc = 0; cc < 3; ++cc) {
            float acc = ib[cc];
            acc = fmaf(z1, AB[0 + cc] + r2 * AB[9  + cc], acc);
            acc = fmaf(z2, AB[3 + cc] + r2 * AB[12 + cc], acc);
            acc = fmaf(z3, AB[6 + cc] + r2 * AB[15 + cc], acc);
            pt[cc] = acc;
            out[OFF_COORD + (size_t)g * 3 + cc] = acc;
        }
        const float ixf = (pt[0] + 1.f) * 0.5f * 31.f;
        const float iyf = (pt[1] + 1.f) * 0.5f * 31.f;
        const float izf = (pt[2] + 1.f) * 0.5f * 31.f;
        const float x0f = floorf(ixf), y0f = floorf(iyf), z0f = floorf(izf);
        const float wx = ixf - x0f, wy = iyf - y0f, wz = izf - z0f;
        const int x0 = (int)x0f, y0 = (int)y0f, z0 = (int)z0f;
        const float* volb = dens + (size_t)b * 32768;
        float s = 0.f;
        #pragma unroll
        for (int dz = 0; dz < 2; ++dz) {
            const int zi = z0 + dz;
            const float wzz = dz ? wz : 1.f - wz;
            #pragma unroll
            for (int dy = 0; dy < 2; ++dy) {
                const int yi = y0 + dy;
                const float wyy = dy ? wy : 1.f - wy;
                #pragma unroll
                for (int dx = 0; dx < 2; ++dx) {
                    const int xi = x0 + dx;
                    const float wxx = dx ? wx : 1.f - wx;
                    if (zi >= 0 && zi < 32 && yi >= 0 && yi < 32 && xi >= 0 && xi < 32)
                        s += wzz * wyy * wxx * volb[zi * 1024 + yi * 32 + xi];
                }
            }
        }
        out[g] = s;
    }
    __syncthreads();

    // ---- per-lane constant setup (identical to round 6) ----
    const int w  = tid >> 6, l = tid & 63;
    const int g0 = w * 256 + 4 * l;          // flat float index within a 4-row stripe
    const int rw = g0 / 384;                 // 0..3: row offset within stripe
    const int c  = g0 - rw * 384;            // channel-quad base (multiple of 4)

    f4v cf0 = {0.f,0.f,0.f,0.f}, cf1 = cf0, cf2 = cf0, cf3 = cf0;
    f4v cf4 = cf0, cf5 = cf0, cf6 = cf0;
    int tb;
    if (c < 128) {
        const int i0 = c >> 1;
        const float ca = sC[i0]     * 0.28209479f;
        const float cb = sC[i0 + 1] * 0.28209479f;
        cf0 = (f4v){ca, 0.f, cb, 0.f};
        cf1 = (f4v){0.f, ca, 0.f, cb};
        tb = 0;
    } else if (c < 256) {
        const int u = (c - 128) >> 1;
        const float a0 = sC[64 + u],     a1 = sC[128 + u],     a2 = sC[192 + u];
        const float b0 = sC[64 + u + 1], b1 = sC[128 + u + 1], b2 = sC[192 + u + 1];
        cf0 = (f4v){a0, 0.f, b0, 0.f};
        cf1 = (f4v){a1, 0.f, b1, 0.f};
        cf2 = (f4v){a2, 0.f, b2, 0.f};
        cf3 = (f4v){0.f, a0, 0.f, b0};
        cf4 = (f4v){0.f, a1, 0.f, b1};
        cf5 = (f4v){0.f, a2, 0.f, b2};
        tb = 8;
    } else if (c < 320) {
        const int i0 = c - 256;
        cf0 = *(const f4v*)&sC[4 * 64 + i0];
        cf1 = *(const f4v*)&sC[5 * 64 + i0];
        cf2 = *(const f4v*)&sC[6 * 64 + i0];
        cf3 = *(const f4v*)&sC[7 * 64 + i0];
        cf4 = *(const f4v*)&sC[8 * 64 + i0];
        tb = 16;
    } else {
        const int i0 = c - 320;
        cf0 = *(const f4v*)&sC[ 9 * 64 + i0];
        cf1 = *(const f4v*)&sC[10 * 64 + i0];
        cf2 = *(const f4v*)&sC[11 * 64 + i0];
        cf3 = *(const f4v*)&sC[12 * 64 + i0];
        cf4 = *(const f4v*)&sC[13 * 64 + i0];
        cf5 = *(const f4v*)&sC[14 * 64 + i0];
        cf6 = *(const f4v*)&sC[15 * 64 + i0];
        tb = 24;
    }

    const float* Tb = sT + tb;
    float* po = out + OFF_CODE + ((size_t)(b * 32768 + vbase)) * 384 + g0;

#define COMPUTE(P, ACC) {                                   \
        const int ro_ = (4 * (P) + rw) * 32;                \
        const f4v ta_  = *(const f4v*)(Tb + ro_);           \
        const f4v tb4_ = *(const f4v*)(Tb + ro_ + 4);       \
        ACC  = cf0 * ta_.x;                                 \
        ACC += cf1 * ta_.y;                                 \
        ACC += cf2 * ta_.z;                                 \
        ACC += cf3 * ta_.w;                                 \
        ACC += cf4 * tb4_.x;                                \
        ACC += cf5 * tb4_.y;                                \
        ACC += cf6 * tb4_.z; }

    // ---- 4 chunks x {compute 4 f4v into regs, store them TWICE} ----
    #pragma unroll
    for (int ch = 0; ch < 4; ++ch) {
        f4v a0, a1, a2, a3;
        COMPUTE(ch * 4 + 0, a0);
        COMPUTE(ch * 4 + 1, a1);
        COMPUTE(ch * 4 + 2, a2);
        COMPUTE(ch * 4 + 3, a3);
        float* pb = po + (size_t)ch * 4 * 1536;
        *(f4v*)(pb + 0)    = a0;
        *(f4v*)(pb + 1536) = a1;
        *(f4v*)(pb + 3072) = a2;
        *(f4v*)(pb + 4608) = a3;
        asm volatile("" ::: "memory");   // keep both store sets (idempotent rewrite)
        *(f4v*)(pb + 0)    = a0;
        *(f4v*)(pb + 1536) = a1;
        *(f4v*)(pb + 3072) = a2;
        *(f4v*)(pb + 4608) = a3;
    }
#undef COMPUTE
}

// ============================================================
extern "C" void kernel_launch(void* const* d_in, const int* in_sizes, int n_in,
                              void* d_out, int out_size, void* d_ws, size_t ws_size,
                              hipStream_t stream) {
    const float* x    = (const float*)d_in[0];
    const float* dens = (const float*)d_in[1];
    const float* F    = (const float*)d_in[2];
    const float* S2   = (const float*)d_in[3];
    const float* bw1  = (const float*)d_in[4];
    const float* bb1  = (const float*)d_in[5];
    const float* bw2  = (const float*)d_in[6];
    const float* bb2  = (const float*)d_in[7];
    const float* cw1  = (const float*)d_in[8];
    const float* cb1  = (const float*)d_in[9];
    const float* cw2  = (const float*)d_in[10];
    const float* cb2  = (const float*)d_in[11];
    const float* iw   = (const float*)d_in[12];
    const float* ib   = (const float*)d_in[13];
    float* out = (float*)d_out;
    float* ws  = (float*)d_ws;

    k_hidden<<<64,   384, 0, stream>>>(F, bw1, bb1, cw1, cb1, ws);
    k_coeffs<<<8,    512, 0, stream>>>(ws, S2, bw2, bb2, cw2, cb2, iw, ws, out + OFF_E);
    k_code<<<4096,   384, 0, stream>>>(x, dens, ws, ib, out);
}